// Round 2
// baseline (2972.815 us; speedup 1.0000x reference)
//
#include <hip/hip_runtime.h>
#include <hip/hip_bf16.h>

// TaylorMap, symmetric-packed quadratic form.
// x_{t+1} = x_t + W0 + W1^T x + sum_{i<=j} x_i x_j (W2[i,j,:]+W2[j,i,:]) , 7 steps.
// Wave roles: (d-tile t, row-parity g). Each wave computes BOTH batch halves
// (two independent MFMA chains) for rows i === g (mod 2), so every A fragment is
// loaded exactly once per CU. Row i needs slices j in [16*(i>>4), 128):
// c(i) = 8 - (i>>4) MFMAs -> 584 slices per d-tile (576 quad + 8 linear)
// vs 1040 unpacked. Partial sums merge across the parity pair via LDS scratch.

#define DSTATE 128
#define BATCH  16384
#define NSTEPS 7
#define BT     64
#define NSL    584          // slices per d-tile (576 sym-quad + 8 linear)
#define G0SL   288          // even-parity rows' slice count (odd rows: 288, linear: 8)

typedef __attribute__((ext_vector_type(8)))  short  short8;   // 8 bf16 = 4 VGPRs
typedef __attribute__((ext_vector_type(16))) float  f32x16;   // MFMA 32x32 C/D

__device__ __forceinline__ unsigned short f2bf(float f){
    unsigned int u = __float_as_uint(f);
    u += 0x7fff + ((u >> 16) & 1);          // RNE
    return (unsigned short)(u >> 16);
}

// Pack symmetric-folded W into bf16 MFMA-A fragments, triangular row lengths.
// Stream order per (t, parity p): rows p, p+2, ... ascending, slices ascending;
// parity-1 region is followed by the linear (W1) row. Fragment layout:
// A[m][k], m=lane&31 -> d=32t+m, k=(lane>>5)*8+e -> j = 16*s + k.
__global__ void prep_kernel(const float* __restrict__ W, short8* __restrict__ A){
    int gid = blockIdx.x * 256 + threadIdx.x;
    const int ntotal = 4 * 129 * 8 * 64;
    if (gid >= ntotal) return;
    int lane = gid & 63; int r = gid >> 6;
    int s = r & 7;  r >>= 3;
    int row = r % 129;
    int t   = r / 129;
    int d  = t * 32 + (lane & 31);
    int kb = (lane >> 5) * 8;
    int dst;
    if (row < 128){
        int sl = row >> 4;
        if (s < sl) return;                  // row i uses slices sl..7 only
        int p = row & 1;
        int M = (row - p) >> 1;              // same-parity rows before this one
        int Q = M >> 3, R = M & 7;
        int off = 8 * M - (4 * Q * (Q - 1) + R * Q);  // prefix sum of c(i')
        dst = t * NSL + p * G0SL + off + (s - sl);
    } else {
        dst = t * NSL + 2 * G0SL + s;        // linear row after odd rows
    }
    union { short8 v; unsigned short u[8]; } fr;
#pragma unroll
    for (int e = 0; e < 8; ++e){
        int j = s * 16 + kb + e;
        float v;
        if (row < 128){
            if      (j < row)  v = 0.0f;
            else if (j == row) v = W[(129 + 128 * row + j) * 128 + d];
            else               v = W[(129 + 128 * row + j) * 128 + d]
                                 + W[(129 + 128 * j + row) * 128 + d];
        } else {
            v = W[(1 + j) * 128 + d];
        }
        fr.u[e] = f2bf(v);
    }
    A[(size_t)dst * 64 + lane] = fr.v;
}

__global__ __launch_bounds__(512, 2)
void taylor_kernel(const float* __restrict__ X, const float* __restrict__ W,
                   const float* __restrict__ tini, const float* __restrict__ lini,
                   const short8* __restrict__ A, float* __restrict__ out)
{
    __shared__ float x_lds[DSTATE * BT];       // fp32 master state, [d][b]
    __shared__ float w0_lds[DSTATE];
    __shared__ float sc_lds[4 * 64 * 17];      // merge scratch, one half at a time

    const int tid  = threadIdx.x;
    const int lane = tid & 63;
    const int w    = tid >> 6;
    const int t    = w & 3;                    // d-tile
    const int g    = w >> 2;                   // row parity
    const int ln   = lane & 31;
    const int hi   = lane >> 5;
    const int b0   = blockIdx.x * BT;

    // ---- init x0 = [X | t_init | l_init] ----
#pragma unroll
    for (int it = 0; it < 16; ++it){
        int entry = tid + it * 512;            // entry = b*128 + d
        int b = entry >> 7, d = entry & 127;
        float v;
        if      (d < 120) v = X[(b0 + b) * 120 + d];
        else if (d < 124) v = tini[d - 120];
        else              v = lini[d - 124];
        x_lds[d * BT + b] = v;
    }
    if (tid < DSTATE) w0_lds[tid] = W[tid];

    const short8* const Aw = A + (size_t)(t * NSL + g * G0SL) * 64 + lane;
    const float sg = (float)g;                 // linear-row scale (0 for g0)

    for (int step = 0; step < NSTEPS; ++step){
        __syncthreads();                       // (A) x_lds stable

        // ---- B fragments, both halves ----
        short8 bfrag[2][8];
#pragma unroll
        for (int h = 0; h < 2; ++h)
#pragma unroll
        for (int s = 0; s < 8; ++s){
            union { short8 v; unsigned short u[8]; } fr;
#pragma unroll
            for (int e = 0; e < 8; ++e){
                int j = s * 16 + hi * 8 + e;
                fr.u[e] = f2bf(x_lds[j * BT + h * 32 + ln]);
            }
            bfrag[h][s] = fr.v;
        }

        // ---- acc init: g0 carries x_old + W0; g1 accumulates a pure partial ----
        f32x16 acc0, acc1;
        if (g == 0){
#pragma unroll
            for (int r = 0; r < 16; ++r){
                int d = 32 * t + (r & 3) + 8 * (r >> 2) + 4 * hi;
                acc0[r] = x_lds[d * BT + ln]      + w0_lds[d];
                acc1[r] = x_lds[d * BT + 32 + ln] + w0_lds[d];
            }
        } else {
#pragma unroll
            for (int r = 0; r < 16; ++r){ acc0[r] = 0.f; acc1[r] = 0.f; }
        }

        // ---- triangular row loop, A double-buffered, static chain lengths ----
        const short8* ap = Aw;
        short8 abuf[2][8];
#pragma unroll
        for (int s = 0; s < 8; ++s) abuf[0][s] = ap[s * 64];
        ap += 8 * 64;
        int irow = g;

#define ROW(C, SL, CUR, NXT, PFC)                                               \
        {                                                                       \
            _Pragma("unroll")                                                   \
            for (int s = 0; s < (PFC); ++s) abuf[NXT][s] = ap[s * 64];          \
            ap += (PFC) * 64;                                                   \
            float s0 = x_lds[irow * BT + ln];                                   \
            float s1 = x_lds[irow * BT + 32 + ln];                              \
            f32x16 Y0 = {}, Y1 = {};                                            \
            _Pragma("unroll")                                                   \
            for (int s = 0; s < (C); ++s)                                       \
                Y0 = __builtin_amdgcn_mfma_f32_32x32x16_bf16(abuf[CUR][s], bfrag[0][(SL) + s], Y0, 0, 0, 0); \
            _Pragma("unroll")                                                   \
            for (int s = 0; s < (C); ++s)                                       \
                Y1 = __builtin_amdgcn_mfma_f32_32x32x16_bf16(abuf[CUR][s], bfrag[1][(SL) + s], Y1, 0, 0, 0); \
            acc0 += s0 * Y0;                                                    \
            acc1 += s1 * Y1;                                                    \
            irow += 2;                                                          \
        }

#define BLOCK(C, SL)                                                            \
        for (int pr = 0; pr < 3; ++pr){ ROW(C, SL, 0, 1, C) ROW(C, SL, 1, 0, C) } \
        ROW(C, SL, 0, 1, C)                                                     \
        ROW(C, SL, 1, 0, ((C) > 1 ? (C) - 1 : 8))

        BLOCK(8, 0) BLOCK(7, 1) BLOCK(6, 2) BLOCK(5, 3)
        BLOCK(4, 4) BLOCK(3, 5) BLOCK(2, 6) BLOCK(1, 7)
#undef ROW
#undef BLOCK

        // linear (W1) row: scale 1 for g1, 0 for g0 (abuf[0] holds its slices
        // for g1 by construction; for g0 it's harmless garbage scaled by 0)
        {
            f32x16 Y0 = {}, Y1 = {};
#pragma unroll
            for (int s = 0; s < 8; ++s){
                Y0 = __builtin_amdgcn_mfma_f32_32x32x16_bf16(abuf[0][s], bfrag[0][s], Y0, 0, 0, 0);
                Y1 = __builtin_amdgcn_mfma_f32_32x32x16_bf16(abuf[0][s], bfrag[1][s], Y1, 0, 0, 0);
            }
            acc0 += sg * Y0;
            acc1 += sg * Y1;
        }

        // ---- merge parity partials (half 0, then half 1) ----
        if (g == 1){
#pragma unroll
            for (int r = 0; r < 16; ++r) sc_lds[(t * 64 + lane) * 17 + r] = acc0[r];
        }
        __syncthreads();                       // (B) x-reads done + scratch h0 visible
        if (g == 0){
#pragma unroll
            for (int r = 0; r < 16; ++r) acc0[r] += sc_lds[(t * 64 + lane) * 17 + r];
        }
        __syncthreads();                       // (C) scratch h0 consumed
        if (g == 1){
#pragma unroll
            for (int r = 0; r < 16; ++r) sc_lds[(t * 64 + lane) * 17 + r] = acc1[r];
        }
        __syncthreads();                       // (D) scratch h1 visible
        if (g == 0){
#pragma unroll
            for (int r = 0; r < 16; ++r) acc1[r] += sc_lds[(t * 64 + lane) * 17 + r];
            if (step < NSTEPS - 1){
#pragma unroll
                for (int r = 0; r < 16; ++r){
                    int d = 32 * t + (r & 3) + 8 * (r >> 2) + 4 * hi;
                    x_lds[d * BT + ln]      = acc0[r];
                    x_lds[d * BT + 32 + ln] = acc1[r];
                }
            } else if (t == 3 && hi == 0){
                // out dims 120..123 = rows 24..27 = regs 12..15 @ hi==0
                *(float4*)(out + (size_t)(b0 + ln) * 4) =
                    make_float4(acc0[12], acc0[13], acc0[14], acc0[15]);
                *(float4*)(out + (size_t)(b0 + 32 + ln) * 4) =
                    make_float4(acc1[12], acc1[13], acc1[14], acc1[15]);
            }
        }
    }
}

extern "C" void kernel_launch(void* const* d_in, const int* in_sizes, int n_in,
                              void* d_out, int out_size, void* d_ws, size_t ws_size,
                              hipStream_t stream)
{
    const float* X  = (const float*)d_in[0];
    const float* W  = (const float*)d_in[1];
    const float* ti = (const float*)d_in[2];
    const float* li = (const float*)d_in[3];
    float* out      = (float*)d_out;
    short8* A       = (short8*)d_ws;           // 4*584*64*16 B = 2.39 MB

    const int ntotal = 4 * 129 * 8 * 64;
    prep_kernel<<<(ntotal + 255) / 256, 256, 0, stream>>>(W, A);
    taylor_kernel<<<BATCH / BT, 512, 0, stream>>>(X, W, ti, li, A, out);
}

// Round 3
// 1510.147 us; speedup vs baseline: 1.9686x; 1.9686x over previous
//
#include <hip/hip_runtime.h>
#include <hip/hip_bf16.h>

// TaylorMap, symmetric-packed quadratic form.
// x_{t+1} = x_t + W0 + W1^T x + sum_{i<=j} x_i x_j (W2[i,j,:]+W2[j,i,:]) , 7 steps.
// Wave roles: (d-tile t, row-parity g). Each wave computes BOTH batch halves
// (two independent MFMA chains) for rows i === g (mod 2), so every A fragment is
// loaded exactly once per CU. Row i needs slices j in [16*(i>>4), 128):
// c(i) = 8 - (i>>4) MFMAs -> 584 slices per d-tile (576 quad + 8 linear).
// R2 post-mortem: __launch_bounds__(512,2) capped the unified RF at ~128 VGPR
// -> ~230-reg demand spilled to scratch (9 GB HBM traffic, 4.7x regression).
// R3: no min-waves cap (free allocation, ~1 block/CU), barriers 4->2/step,
// g0 skips the zero-scaled linear row.

#define DSTATE 128
#define BATCH  16384
#define NSTEPS 7
#define BT     64
#define NSL    584          // slices per d-tile (576 sym-quad + 8 linear)
#define G0SL   288          // even-parity rows' slice count (odd rows: 288, linear: 8)

typedef __attribute__((ext_vector_type(8)))  short  short8;   // 8 bf16 = 4 VGPRs
typedef __attribute__((ext_vector_type(16))) float  f32x16;   // MFMA 32x32 C/D

__device__ __forceinline__ unsigned short f2bf(float f){
    unsigned int u = __float_as_uint(f);
    u += 0x7fff + ((u >> 16) & 1);          // RNE
    return (unsigned short)(u >> 16);
}

// Pack symmetric-folded W into bf16 MFMA-A fragments, triangular row lengths.
// Stream order per (t, parity p): rows p, p+2, ... ascending, slices ascending;
// parity-1 region is followed by the linear (W1) row. Fragment layout:
// A[m][k], m=lane&31 -> d=32t+m, k=(lane>>5)*8+e -> j = 16*s + k.
__global__ void prep_kernel(const float* __restrict__ W, short8* __restrict__ A){
    int gid = blockIdx.x * 256 + threadIdx.x;
    const int ntotal = 4 * 129 * 8 * 64;
    if (gid >= ntotal) return;
    int lane = gid & 63; int r = gid >> 6;
    int s = r & 7;  r >>= 3;
    int row = r % 129;
    int t   = r / 129;
    int d  = t * 32 + (lane & 31);
    int kb = (lane >> 5) * 8;
    int dst;
    if (row < 128){
        int sl = row >> 4;
        if (s < sl) return;                  // row i uses slices sl..7 only
        int p = row & 1;
        int M = (row - p) >> 1;              // same-parity rows before this one
        int Q = M >> 3, R = M & 7;
        int off = 8 * M - (4 * Q * (Q - 1) + R * Q);  // prefix sum of c(i')
        dst = t * NSL + p * G0SL + off + (s - sl);
    } else {
        dst = t * NSL + 2 * G0SL + s;        // linear row after odd rows
    }
    union { short8 v; unsigned short u[8]; } fr;
#pragma unroll
    for (int e = 0; e < 8; ++e){
        int j = s * 16 + kb + e;
        float v;
        if (row < 128){
            if      (j < row)  v = 0.0f;
            else if (j == row) v = W[(129 + 128 * row + j) * 128 + d];
            else               v = W[(129 + 128 * row + j) * 128 + d]
                                 + W[(129 + 128 * j + row) * 128 + d];
        } else {
            v = W[(1 + j) * 128 + d];
        }
        fr.u[e] = f2bf(v);
    }
    A[(size_t)dst * 64 + lane] = fr.v;
}

__global__ __launch_bounds__(512)
void taylor_kernel(const float* __restrict__ X, const float* __restrict__ W,
                   const float* __restrict__ tini, const float* __restrict__ lini,
                   const short8* __restrict__ A, float* __restrict__ out)
{
    __shared__ float x_lds[DSTATE * BT];       // fp32 master state, [d][b]
    __shared__ float w0_lds[DSTATE];
    __shared__ float sc_lds[2][4 * 64 * 17];   // merge scratch, both halves

    const int tid  = threadIdx.x;
    const int lane = tid & 63;
    const int w    = tid >> 6;
    const int t    = w & 3;                    // d-tile
    const int g    = w >> 2;                   // row parity
    const int ln   = lane & 31;
    const int hi   = lane >> 5;
    const int b0   = blockIdx.x * BT;

    // ---- init x0 = [X | t_init | l_init] ----
#pragma unroll
    for (int it = 0; it < 16; ++it){
        int entry = tid + it * 512;            // entry = b*128 + d
        int b = entry >> 7, d = entry & 127;
        float v;
        if      (d < 120) v = X[(b0 + b) * 120 + d];
        else if (d < 124) v = tini[d - 120];
        else              v = lini[d - 124];
        x_lds[d * BT + b] = v;
    }
    if (tid < DSTATE) w0_lds[tid] = W[tid];

    const short8* const Aw = A + (size_t)(t * NSL + g * G0SL) * 64 + lane;

    for (int step = 0; step < NSTEPS; ++step){
        __syncthreads();                       // (A) x_lds stable

        // ---- B fragments, both halves ----
        short8 bfrag[2][8];
#pragma unroll
        for (int h = 0; h < 2; ++h)
#pragma unroll
        for (int s = 0; s < 8; ++s){
            union { short8 v; unsigned short u[8]; } fr;
#pragma unroll
            for (int e = 0; e < 8; ++e){
                int j = s * 16 + hi * 8 + e;
                fr.u[e] = f2bf(x_lds[j * BT + h * 32 + ln]);
            }
            bfrag[h][s] = fr.v;
        }

        // ---- acc init: g0 carries x_old + W0; g1 accumulates a pure partial ----
        f32x16 acc0, acc1;
        if (g == 0){
#pragma unroll
            for (int r = 0; r < 16; ++r){
                int d = 32 * t + (r & 3) + 8 * (r >> 2) + 4 * hi;
                acc0[r] = x_lds[d * BT + ln]      + w0_lds[d];
                acc1[r] = x_lds[d * BT + 32 + ln] + w0_lds[d];
            }
        } else {
#pragma unroll
            for (int r = 0; r < 16; ++r){ acc0[r] = 0.f; acc1[r] = 0.f; }
        }

        // ---- triangular row loop, A double-buffered, static chain lengths ----
        const short8* ap = Aw;
        short8 abuf[2][8];
#pragma unroll
        for (int s = 0; s < 8; ++s) abuf[0][s] = ap[s * 64];
        ap += 8 * 64;
        int irow = g;

#define ROW(C, SL, CUR, NXT, PFC)                                               \
        {                                                                       \
            _Pragma("unroll")                                                   \
            for (int s = 0; s < (PFC); ++s) abuf[NXT][s] = ap[s * 64];          \
            ap += (PFC) * 64;                                                   \
            float s0 = x_lds[irow * BT + ln];                                   \
            float s1 = x_lds[irow * BT + 32 + ln];                              \
            f32x16 Y0 = {}, Y1 = {};                                            \
            _Pragma("unroll")                                                   \
            for (int s = 0; s < (C); ++s)                                       \
                Y0 = __builtin_amdgcn_mfma_f32_32x32x16_bf16(abuf[CUR][s], bfrag[0][(SL) + s], Y0, 0, 0, 0); \
            _Pragma("unroll")                                                   \
            for (int s = 0; s < (C); ++s)                                       \
                Y1 = __builtin_amdgcn_mfma_f32_32x32x16_bf16(abuf[CUR][s], bfrag[1][(SL) + s], Y1, 0, 0, 0); \
            acc0 += s0 * Y0;                                                    \
            acc1 += s1 * Y1;                                                    \
            irow += 2;                                                          \
        }

#define BLOCK(C, SL)                                                            \
        for (int pr = 0; pr < 3; ++pr){ ROW(C, SL, 0, 1, C) ROW(C, SL, 1, 0, C) } \
        ROW(C, SL, 0, 1, C)                                                     \
        ROW(C, SL, 1, 0, ((C) > 1 ? (C) - 1 : 8))

        BLOCK(8, 0) BLOCK(7, 1) BLOCK(6, 2) BLOCK(5, 3)
        BLOCK(4, 4) BLOCK(3, 5) BLOCK(2, 6) BLOCK(1, 7)
#undef ROW
#undef BLOCK

        // linear (W1) row: only g1 (scale 1); g0's would be scaled by 0 -> skip
        if (g){
            f32x16 Y0 = {}, Y1 = {};
#pragma unroll
            for (int s = 0; s < 8; ++s){
                Y0 = __builtin_amdgcn_mfma_f32_32x32x16_bf16(abuf[0][s], bfrag[0][s], Y0, 0, 0, 0);
                Y1 = __builtin_amdgcn_mfma_f32_32x32x16_bf16(abuf[0][s], bfrag[1][s], Y1, 0, 0, 0);
            }
            acc0 += Y0;
            acc1 += Y1;
            // write both half-partials, single barrier
#pragma unroll
            for (int r = 0; r < 16; ++r){
                sc_lds[0][(t * 64 + lane) * 17 + r] = acc0[r];
                sc_lds[1][(t * 64 + lane) * 17 + r] = acc1[r];
            }
        }

        __syncthreads();                       // (B) x reads done + scratch visible
        if (g == 0){
#pragma unroll
            for (int r = 0; r < 16; ++r){
                acc0[r] += sc_lds[0][(t * 64 + lane) * 17 + r];
                acc1[r] += sc_lds[1][(t * 64 + lane) * 17 + r];
            }
            if (step < NSTEPS - 1){
#pragma unroll
                for (int r = 0; r < 16; ++r){
                    int d = 32 * t + (r & 3) + 8 * (r >> 2) + 4 * hi;
                    x_lds[d * BT + ln]      = acc0[r];
                    x_lds[d * BT + 32 + ln] = acc1[r];
                }
            } else if (t == 3 && hi == 0){
                // out dims 120..123 = rows 24..27 = regs 12..15 @ hi==0
                *(float4*)(out + (size_t)(b0 + ln) * 4) =
                    make_float4(acc0[12], acc0[13], acc0[14], acc0[15]);
                *(float4*)(out + (size_t)(b0 + 32 + ln) * 4) =
                    make_float4(acc1[12], acc1[13], acc1[14], acc1[15]);
            }
        }
        // next loop iteration's barrier (A) orders g0's x-write/scratch-read
        // against g1's next bfrag-build/scratch-write
    }
}

extern "C" void kernel_launch(void* const* d_in, const int* in_sizes, int n_in,
                              void* d_out, int out_size, void* d_ws, size_t ws_size,
                              hipStream_t stream)
{
    const float* X  = (const float*)d_in[0];
    const float* W  = (const float*)d_in[1];
    const float* ti = (const float*)d_in[2];
    const float* li = (const float*)d_in[3];
    float* out      = (float*)d_out;
    short8* A       = (short8*)d_ws;           // 4*584*64*16 B = 2.39 MB

    const int ntotal = 4 * 129 * 8 * 64;
    prep_kernel<<<(ntotal + 255) / 256, 256, 0, stream>>>(W, A);
    taylor_kernel<<<BATCH / BT, 512, 0, stream>>>(X, W, ti, li, A, out);
}

// Round 4
// 1507.266 us; speedup vs baseline: 1.9723x; 1.0019x over previous
//
#include <hip/hip_runtime.h>
#include <hip/hip_bf16.h>

// TaylorMap, symmetric-packed quadratic form.
// x_{t+1} = x_t + W0 + W1^T x + sum_{i<=j} x_i x_j (W2[i,j,:]+W2[j,i,:]) , 7 steps.
// Wave roles: (d-tile t, row-parity g). Each wave computes BOTH batch halves
// for rows i === g (mod 2), so every A fragment is loaded once per CU.
// Row i needs slices j in [16*(i>>4), 128): c(i) = 8 - (i>>4) MFMAs
// -> 584 slices per d-tile (576 quad + 8 linear) vs 1040 unpacked.
// R2 post-mortem: __launch_bounds__(512,2) = min 2 BLOCKS/CU -> 128-reg cap -> spill.
// R3 post-mortem: with no hint, backend derives reg target from LDS-bounded
// occupancy (68KB LDS -> 2 blocks/CU -> 4 waves/SIMD -> 128-reg cap) -> still spills.
// R4: amdgpu_waves_per_eu(2) pins min 2 waves/SIMD -> 256-reg cap; demand ~210 fits.

#define DSTATE 128
#define BATCH  16384
#define NSTEPS 7
#define BT     64
#define NSL    584          // slices per d-tile (576 sym-quad + 8 linear)
#define G0SL   288          // even-parity rows' slice count (odd: 288, linear: 8)

typedef __attribute__((ext_vector_type(8)))  short  short8;   // 8 bf16 = 4 VGPRs
typedef __attribute__((ext_vector_type(16))) float  f32x16;   // MFMA 32x32 C/D

__device__ __forceinline__ unsigned short f2bf(float f){
    unsigned int u = __float_as_uint(f);
    u += 0x7fff + ((u >> 16) & 1);          // RNE
    return (unsigned short)(u >> 16);
}

// Pack symmetric-folded W into bf16 MFMA-A fragments, triangular row lengths.
// Stream order per (t, parity p): rows p, p+2, ... ascending, slices ascending;
// parity-1 region is followed by the linear (W1) row. Fragment layout:
// A[m][k], m=lane&31 -> d=32t+m, k=(lane>>5)*8+e -> j = 16*s + k.
__global__ void prep_kernel(const float* __restrict__ W, short8* __restrict__ A){
    int gid = blockIdx.x * 256 + threadIdx.x;
    const int ntotal = 4 * 129 * 8 * 64;
    if (gid >= ntotal) return;
    int lane = gid & 63; int r = gid >> 6;
    int s = r & 7;  r >>= 3;
    int row = r % 129;
    int t   = r / 129;
    int d  = t * 32 + (lane & 31);
    int kb = (lane >> 5) * 8;
    int dst;
    if (row < 128){
        int sl = row >> 4;
        if (s < sl) return;                  // row i uses slices sl..7 only
        int p = row & 1;
        int M = (row - p) >> 1;              // same-parity rows before this one
        int Q = M >> 3, R = M & 7;
        int off = 8 * M - (4 * Q * (Q - 1) + R * Q);  // prefix sum of c(i')
        dst = t * NSL + p * G0SL + off + (s - sl);
    } else {
        dst = t * NSL + 2 * G0SL + s;        // linear row after odd rows
    }
    union { short8 v; unsigned short u[8]; } fr;
#pragma unroll
    for (int e = 0; e < 8; ++e){
        int j = s * 16 + kb + e;
        float v;
        if (row < 128){
            if      (j < row)  v = 0.0f;
            else if (j == row) v = W[(129 + 128 * row + j) * 128 + d];
            else               v = W[(129 + 128 * row + j) * 128 + d]
                                 + W[(129 + 128 * j + row) * 128 + d];
        } else {
            v = W[(1 + j) * 128 + d];
        }
        fr.u[e] = f2bf(v);
    }
    A[(size_t)dst * 64 + lane] = fr.v;
}

__global__ __launch_bounds__(512)
__attribute__((amdgpu_waves_per_eu(2)))
void taylor_kernel(const float* __restrict__ X, const float* __restrict__ W,
                   const float* __restrict__ tini, const float* __restrict__ lini,
                   const short8* __restrict__ A, float* __restrict__ out)
{
    __shared__ float x_lds[DSTATE * BT];       // fp32 master state, [d][b]
    __shared__ float w0_lds[DSTATE];
    __shared__ float sc_lds[2][4 * 64 * 17];   // merge scratch, both halves

    const int tid  = threadIdx.x;
    const int lane = tid & 63;
    const int w    = tid >> 6;
    const int t    = w & 3;                    // d-tile
    const int g    = w >> 2;                   // row parity
    const int ln   = lane & 31;
    const int hi   = lane >> 5;
    const int b0   = blockIdx.x * BT;

    // ---- init x0 = [X | t_init | l_init] ----
#pragma unroll
    for (int it = 0; it < 16; ++it){
        int entry = tid + it * 512;            // entry = b*128 + d
        int b = entry >> 7, d = entry & 127;
        float v;
        if      (d < 120) v = X[(b0 + b) * 120 + d];
        else if (d < 124) v = tini[d - 120];
        else              v = lini[d - 124];
        x_lds[d * BT + b] = v;
    }
    if (tid < DSTATE) w0_lds[tid] = W[tid];

    const short8* const Aw = A + (size_t)(t * NSL + g * G0SL) * 64 + lane;

#pragma unroll 1
    for (int step = 0; step < NSTEPS; ++step){
        __syncthreads();                       // (A) x_lds stable

        // ---- B fragments, both halves ----
        short8 bfrag[2][8];
#pragma unroll
        for (int h = 0; h < 2; ++h)
#pragma unroll
        for (int s = 0; s < 8; ++s){
            union { short8 v; unsigned short u[8]; } fr;
#pragma unroll
            for (int e = 0; e < 8; ++e){
                int j = s * 16 + hi * 8 + e;
                fr.u[e] = f2bf(x_lds[j * BT + h * 32 + ln]);
            }
            bfrag[h][s] = fr.v;
        }

        // ---- acc init: g0 carries x_old + W0; g1 accumulates a pure partial ----
        f32x16 acc0, acc1;
        if (g == 0){
#pragma unroll
            for (int r = 0; r < 16; ++r){
                int d = 32 * t + (r & 3) + 8 * (r >> 2) + 4 * hi;
                acc0[r] = x_lds[d * BT + ln]      + w0_lds[d];
                acc1[r] = x_lds[d * BT + 32 + ln] + w0_lds[d];
            }
        } else {
#pragma unroll
            for (int r = 0; r < 16; ++r){ acc0[r] = 0.f; acc1[r] = 0.f; }
        }

        // ---- triangular row loop, A double-buffered, static chain lengths ----
        const short8* ap = Aw;
        short8 abuf[2][8];
#pragma unroll
        for (int s = 0; s < 8; ++s) abuf[0][s] = ap[s * 64];
        ap += 8 * 64;
        int irow = g;

#define ROW(C, SL, CUR, NXT, PFC)                                               \
        {                                                                       \
            _Pragma("unroll")                                                   \
            for (int s = 0; s < (PFC); ++s) abuf[NXT][s] = ap[s * 64];          \
            ap += (PFC) * 64;                                                   \
            float s0 = x_lds[irow * BT + ln];                                   \
            float s1 = x_lds[irow * BT + 32 + ln];                              \
            f32x16 Y0 = {}, Y1 = {};                                            \
            _Pragma("unroll")                                                   \
            for (int s = 0; s < (C); ++s)                                       \
                Y0 = __builtin_amdgcn_mfma_f32_32x32x16_bf16(abuf[CUR][s], bfrag[0][(SL) + s], Y0, 0, 0, 0); \
            _Pragma("unroll")                                                   \
            for (int s = 0; s < (C); ++s)                                       \
                Y1 = __builtin_amdgcn_mfma_f32_32x32x16_bf16(abuf[CUR][s], bfrag[1][(SL) + s], Y1, 0, 0, 0); \
            acc0 += s0 * Y0;                                                    \
            acc1 += s1 * Y1;                                                    \
            irow += 2;                                                          \
        }

#define BLOCK(C, SL)                                                            \
        for (int pr = 0; pr < 3; ++pr){ ROW(C, SL, 0, 1, C) ROW(C, SL, 1, 0, C) } \
        ROW(C, SL, 0, 1, C)                                                     \
        ROW(C, SL, 1, 0, ((C) > 1 ? (C) - 1 : 8))

        BLOCK(8, 0) BLOCK(7, 1) BLOCK(6, 2) BLOCK(5, 3)
        BLOCK(4, 4) BLOCK(3, 5) BLOCK(2, 6) BLOCK(1, 7)
#undef ROW
#undef BLOCK

        // linear (W1) row: only g1 (scale 1); g0's would be scaled by 0 -> skip
        if (g){
            f32x16 Y0 = {}, Y1 = {};
#pragma unroll
            for (int s = 0; s < 8; ++s){
                Y0 = __builtin_amdgcn_mfma_f32_32x32x16_bf16(abuf[0][s], bfrag[0][s], Y0, 0, 0, 0);
                Y1 = __builtin_amdgcn_mfma_f32_32x32x16_bf16(abuf[0][s], bfrag[1][s], Y1, 0, 0, 0);
            }
            acc0 += Y0;
            acc1 += Y1;
            // write both half-partials, single barrier
#pragma unroll
            for (int r = 0; r < 16; ++r){
                sc_lds[0][(t * 64 + lane) * 17 + r] = acc0[r];
                sc_lds[1][(t * 64 + lane) * 17 + r] = acc1[r];
            }
        }

        __syncthreads();                       // (B) x reads done + scratch visible
        if (g == 0){
#pragma unroll
            for (int r = 0; r < 16; ++r){
                acc0[r] += sc_lds[0][(t * 64 + lane) * 17 + r];
                acc1[r] += sc_lds[1][(t * 64 + lane) * 17 + r];
            }
            if (step < NSTEPS - 1){
#pragma unroll
                for (int r = 0; r < 16; ++r){
                    int d = 32 * t + (r & 3) + 8 * (r >> 2) + 4 * hi;
                    x_lds[d * BT + ln]      = acc0[r];
                    x_lds[d * BT + 32 + ln] = acc1[r];
                }
            } else if (t == 3 && hi == 0){
                // out dims 120..123 = rows 24..27 = regs 12..15 @ hi==0
                *(float4*)(out + (size_t)(b0 + ln) * 4) =
                    make_float4(acc0[12], acc0[13], acc0[14], acc0[15]);
                *(float4*)(out + (size_t)(b0 + 32 + ln) * 4) =
                    make_float4(acc1[12], acc1[13], acc1[14], acc1[15]);
            }
        }
        // next loop iteration's barrier (A) orders g0's x-write/scratch-read
        // against g1's next bfrag-build/scratch-write
    }
}

extern "C" void kernel_launch(void* const* d_in, const int* in_sizes, int n_in,
                              void* d_out, int out_size, void* d_ws, size_t ws_size,
                              hipStream_t stream)
{
    const float* X  = (const float*)d_in[0];
    const float* W  = (const float*)d_in[1];
    const float* ti = (const float*)d_in[2];
    const float* li = (const float*)d_in[3];
    float* out      = (float*)d_out;
    short8* A       = (short8*)d_ws;           // 4*584*64*16 B = 2.39 MB

    const int ntotal = 4 * 129 * 8 * 64;
    prep_kernel<<<(ntotal + 255) / 256, 256, 0, stream>>>(W, A);
    taylor_kernel<<<BATCH / BT, 512, 0, stream>>>(X, W, ti, li, A, out);
}